// Round 1
// baseline (855.461 us; speedup 1.0000x reference)
//
#include <hip/hip_runtime.h>
#include <math.h>

#define Bn  65536
#define Dn  512
#define Kn  64
#define H1n 256
#define H2n 128
#define BM  16   // rows per block

__global__ void zero_out_k(float* out) { out[0] = 0.0f; }

__global__ __launch_bounds__(256)
void llp_fused(const float* __restrict__ x,
               const float* __restrict__ label,
               const float* __restrict__ u,
               const float* __restrict__ W1, const float* __restrict__ b1,
               const float* __restrict__ W2, const float* __restrict__ b2,
               const float* __restrict__ W3, const float* __restrict__ b3,
               const float* __restrict__ thetas,
               const int* __restrict__ epoch_p,
               float* __restrict__ out)
{
    // LDS layout (floats). Phase 1 live: xs[16][512] + h1s[16][256] + xts[16][64]
    // Phase 2+: h2s[16][128] and lgs[16][64] alias the dead xs region.
    __shared__ float smem[BM*Dn + BM*H1n + BM*Kn]; // 13312 floats = 53 KB -> 3 blocks/CU
    float* xs  = smem;                    // [BM][512]
    float* h1s = smem + BM*Dn;            // [BM][256]
    float* xts = smem + BM*Dn + BM*H1n;   // [BM][64]
    float* h2s = smem;                    // alias, [BM][128]
    float* lgs = smem + BM*H2n;           // alias, [BM][64]

    const int tid  = threadIdx.x;
    const int row0 = blockIdx.x * BM;

    // ---- stage x tile: 8192 floats = 2048 float4, 8 per thread, coalesced ----
    {
        const float4* xg  = (const float4*)(x + (size_t)row0 * Dn);
        float4*       xls = (float4*)xs;
        #pragma unroll
        for (int i = 0; i < 8; ++i)
            xls[tid + i * 256] = xg[tid + i * 256];
    }
    __syncthreads();

    // ---- phase h1: relu(x @ W1 + b1), 4x4 register tile ----
    {
        const int cg = tid & 63;   // col group -> cols cg*4 .. +3
        const int rg = tid >> 6;   // row group -> rows rg*4 .. +3
        const float4* W1v = (const float4*)W1;
        const float4  bv  = ((const float4*)b1)[cg];
        float acc[4][4];
        #pragma unroll
        for (int i = 0; i < 4; ++i) {
            acc[i][0] = bv.x; acc[i][1] = bv.y; acc[i][2] = bv.z; acc[i][3] = bv.w;
        }
        for (int d = 0; d < Dn; d += 4) {
            float4 xv[4];
            #pragma unroll
            for (int i = 0; i < 4; ++i)
                xv[i] = *(const float4*)&xs[(rg*4 + i)*Dn + d];
            #pragma unroll
            for (int dd = 0; dd < 4; ++dd) {
                const float4 wv = W1v[(size_t)(d + dd) * (H1n/4) + cg];
                #pragma unroll
                for (int i = 0; i < 4; ++i) {
                    const float xx = ((const float*)&xv[i])[dd];
                    acc[i][0] = fmaf(xx, wv.x, acc[i][0]);
                    acc[i][1] = fmaf(xx, wv.y, acc[i][1]);
                    acc[i][2] = fmaf(xx, wv.z, acc[i][2]);
                    acc[i][3] = fmaf(xx, wv.w, acc[i][3]);
                }
            }
        }
        #pragma unroll
        for (int i = 0; i < 4; ++i) {
            float4 o;
            o.x = fmaxf(acc[i][0], 0.f);
            o.y = fmaxf(acc[i][1], 0.f);
            o.z = fmaxf(acc[i][2], 0.f);
            o.w = fmaxf(acc[i][3], 0.f);
            *(float4*)&h1s[(rg*4 + i)*H1n + cg*4] = o;
        }
    }

    // ---- phase xt: x @ thetas (no bias, no relu), 1x4 tile ----
    {
        const int cg = tid & 15;   // cols cg*4 .. +3 of 64
        const int rr = tid >> 4;   // row 0..15
        const float4* Tv = (const float4*)thetas;
        float a0 = 0.f, a1 = 0.f, a2 = 0.f, a3 = 0.f;
        for (int d = 0; d < Dn; d += 4) {
            const float4 xv = *(const float4*)&xs[rr*Dn + d];
            #pragma unroll
            for (int dd = 0; dd < 4; ++dd) {
                const float4 tv = Tv[(size_t)(d + dd) * (Kn/4) + cg];
                const float xx = ((const float*)&xv)[dd];
                a0 = fmaf(xx, tv.x, a0);
                a1 = fmaf(xx, tv.y, a1);
                a2 = fmaf(xx, tv.z, a2);
                a3 = fmaf(xx, tv.w, a3);
            }
        }
        xts[rr*Kn + cg*4 + 0] = a0;
        xts[rr*Kn + cg*4 + 1] = a1;
        xts[rr*Kn + cg*4 + 2] = a2;
        xts[rr*Kn + cg*4 + 3] = a3;
    }
    __syncthreads();   // xs now dead; h1s, xts complete

    // ---- phase h2: relu(h1 @ W2 + b2), 2x4 tile; writes alias xs region ----
    {
        const int cg = tid & 31;   // cols cg*4 .. +3 of 128
        const int rg = tid >> 5;   // rows rg*2 .. +1
        const float4* W2v = (const float4*)W2;
        const float4  bv  = ((const float4*)b2)[cg];
        float acc[2][4];
        #pragma unroll
        for (int i = 0; i < 2; ++i) {
            acc[i][0] = bv.x; acc[i][1] = bv.y; acc[i][2] = bv.z; acc[i][3] = bv.w;
        }
        for (int d = 0; d < H1n; d += 4) {
            float4 xv[2];
            #pragma unroll
            for (int i = 0; i < 2; ++i)
                xv[i] = *(const float4*)&h1s[(rg*2 + i)*H1n + d];
            #pragma unroll
            for (int dd = 0; dd < 4; ++dd) {
                const float4 wv = W2v[(size_t)(d + dd) * (H2n/4) + cg];
                #pragma unroll
                for (int i = 0; i < 2; ++i) {
                    const float xx = ((const float*)&xv[i])[dd];
                    acc[i][0] = fmaf(xx, wv.x, acc[i][0]);
                    acc[i][1] = fmaf(xx, wv.y, acc[i][1]);
                    acc[i][2] = fmaf(xx, wv.z, acc[i][2]);
                    acc[i][3] = fmaf(xx, wv.w, acc[i][3]);
                }
            }
        }
        __syncthreads(); // ensure all reads of xs done before overwriting (alias)
        #pragma unroll
        for (int i = 0; i < 2; ++i) {
            float4 o;
            o.x = fmaxf(acc[i][0], 0.f);
            o.y = fmaxf(acc[i][1], 0.f);
            o.z = fmaxf(acc[i][2], 0.f);
            o.w = fmaxf(acc[i][3], 0.f);
            *(float4*)&h2s[(rg*2 + i)*H2n + cg*4] = o;
        }
    }
    __syncthreads();

    // ---- phase logits: h2 @ W3 + b3, 1x4 tile ----
    {
        const int cg = tid & 15;   // cols cg*4 .. +3 of 64
        const int rr = tid >> 4;   // row 0..15
        const float4* W3v = (const float4*)W3;
        const float4  bv  = ((const float4*)b3)[cg];
        float a0 = bv.x, a1 = bv.y, a2 = bv.z, a3 = bv.w;
        for (int d = 0; d < H2n; d += 4) {
            const float4 xv = *(const float4*)&h2s[rr*H2n + d];
            #pragma unroll
            for (int dd = 0; dd < 4; ++dd) {
                const float4 wv = W3v[(size_t)(d + dd) * (Kn/4) + cg];
                const float xx = ((const float*)&xv)[dd];
                a0 = fmaf(xx, wv.x, a0);
                a1 = fmaf(xx, wv.y, a1);
                a2 = fmaf(xx, wv.z, a2);
                a3 = fmaf(xx, wv.w, a3);
            }
        }
        lgs[rr*Kn + cg*4 + 0] = a0;
        lgs[rr*Kn + cg*4 + 1] = a1;
        lgs[rr*Kn + cg*4 + 2] = a2;
        lgs[rr*Kn + cg*4 + 3] = a3;
    }
    __syncthreads();

    // ---- softmax + weighted sum + loss. One wave (64 lanes == K) per 4 rows ----
    {
        const int wave = tid >> 6;   // 0..3
        const int lane = tid & 63;

        const int ep = *epoch_p;
        float t = 10.0f * powf(0.01f, (float)ep * (1.0f / 1000.0f));
        const float temp = fmaxf(0.1f, t);
        const float inv_temp = 1.0f / temp;

        float partial = 0.0f;
        #pragma unroll
        for (int rr2 = 0; rr2 < 4; ++rr2) {
            const int r   = wave * 4 + rr2;
            const int row = row0 + r;
            const float lo = lgs[r*Kn + lane];
            const float uu = u[(size_t)row * Kn + lane];
            const float g  = -logf(-logf(uu));
            float s = (lo + g) * inv_temp;
            // max-reduce over 64 lanes
            float m = s;
            #pragma unroll
            for (int off = 32; off > 0; off >>= 1)
                m = fmaxf(m, __shfl_xor(m, off));
            const float e = expf(s - m);
            float sum = e;
            #pragma unroll
            for (int off = 32; off > 0; off >>= 1)
                sum += __shfl_xor(sum, off);
            float v = (e / sum) * xts[r*Kn + lane];
            #pragma unroll
            for (int off = 32; off > 0; off >>= 1)
                v += __shfl_xor(v, off);
            if (lane == 0) {
                const float diff = v - label[row];
                partial = fmaf(diff, diff, partial);
            }
        }
        if (lane == 0)
            atomicAdd(out, partial * (1.0f / (float)Bn));
    }
}

extern "C" void kernel_launch(void* const* d_in, const int* in_sizes, int n_in,
                              void* d_out, int out_size, void* d_ws, size_t ws_size,
                              hipStream_t stream) {
    const float* x      = (const float*)d_in[0];
    const float* label  = (const float*)d_in[1];
    const float* u      = (const float*)d_in[2];
    const float* W1     = (const float*)d_in[3];
    const float* b1     = (const float*)d_in[4];
    const float* W2     = (const float*)d_in[5];
    const float* b2     = (const float*)d_in[6];
    const float* W3     = (const float*)d_in[7];
    const float* b3     = (const float*)d_in[8];
    const float* thetas = (const float*)d_in[9];
    const int*   epoch  = (const int*)d_in[10];
    float* out = (float*)d_out;

    // d_out is re-poisoned (0xAA) before every timed replay -> must zero it here.
    zero_out_k<<<1, 1, 0, stream>>>(out);
    llp_fused<<<Bn / BM, 256, 0, stream>>>(x, label, u, W1, b1, W2, b2, W3, b3,
                                           thetas, epoch, out);
}

// Round 2
// 400.042 us; speedup vs baseline: 2.1384x; 2.1384x over previous
//
#include <hip/hip_runtime.h>
#include <math.h>

#define Bn  65536
#define Dn  512
#define Kn  64
#define H1n 256
#define H2n 128
#define BM  32   // rows per block

typedef short bf16x8 __attribute__((ext_vector_type(8)));
typedef float floatx4 __attribute__((ext_vector_type(4)));

__device__ __forceinline__ unsigned short f2bf(float f) {
    unsigned u = __builtin_bit_cast(unsigned, f);
    u += 0x7FFF + ((u >> 16) & 1);   // round-to-nearest-even
    return (unsigned short)(u >> 16);
}

// ---- prep: transpose+convert weights to bf16 [N][K] layout in ws; zero out ----
// ws layout (ushort elems): W1t[256][512] @0, Tt[64][512] @131072,
//                           W2t[128][256] @163840, W3t[64][128] @196608
__global__ __launch_bounds__(256)
void prep_k(const float* __restrict__ W1, const float* __restrict__ W2,
            const float* __restrict__ W3, const float* __restrict__ Th,
            unsigned short* __restrict__ ws, float* __restrict__ out)
{
    const int gid = blockIdx.x * 256 + threadIdx.x;
    if (gid == 0) out[0] = 0.0f;
    if (gid < 131072) {                       // W1t[n][k] = W1[k][n], n<256 k<512
        const int n = gid >> 9, k = gid & 511;
        ws[gid] = f2bf(W1[k * H1n + n]);
    } else if (gid < 163840) {                // Tt[n][k] = Th[k][n], n<64 k<512
        const int i = gid - 131072, n = i >> 9, k = i & 511;
        ws[gid] = f2bf(Th[k * Kn + n]);
    } else if (gid < 196608) {                // W2t[n][k] = W2[k][n], n<128 k<256
        const int i = gid - 163840, n = i >> 8, k = i & 255;
        ws[gid] = f2bf(W2[k * H2n + n]);
    } else if (gid < 204800) {                // W3t[n][k] = W3[k][n], n<64 k<128
        const int i = gid - 196608, n = i >> 7, k = i & 127;
        ws[gid] = f2bf(W3[k * Kn + n]);
    }
}

// LDS map (bytes), total 49152 -> 3 blocks/CU:
//  region1 [0..32768): phase1 = xA: 32 rows x 64 chunks(16B) XOR-swizzled
//                      phase2+ = xt f32[32][68] @0 (8704), lg f32[32][68] @8704 (8704),
//                                h2A 32x16 chunks swizzled @17408 (8192)
//  region2 [32768..49152): h1A: 32 rows x 32 chunks swizzled
__global__ __launch_bounds__(256)
void llp_mfma(const float* __restrict__ x,
              const float* __restrict__ label,
              const float* __restrict__ u,
              const float* __restrict__ b1, const float* __restrict__ b2,
              const float* __restrict__ b3,
              const unsigned short* __restrict__ W1t,
              const unsigned short* __restrict__ Tt,
              const unsigned short* __restrict__ W2t,
              const unsigned short* __restrict__ W3t,
              const int* __restrict__ epoch_p,
              float* __restrict__ out)
{
    __shared__ char smem[49152];

    const int tid  = threadIdx.x;
    const int row0 = blockIdx.x * BM;
    const int w    = tid >> 6;      // wave 0..3
    const int lane = tid & 63;
    const int lrow = lane & 15;     // MFMA fragment row/col-in-tile
    const int quad = lane >> 4;     // MFMA k-quad
    const int rg   = w >> 1;        // row group: rows rg*16..+15
    const int ch   = w & 1;         // column half

    // ---- stage x tile -> bf16 LDS in A-fragment layout (XOR swizzle) ----
    {
        const float4* xg = (const float4*)(x + (size_t)row0 * Dn);
        #pragma unroll
        for (int i = 0; i < 16; ++i) {
            const int f = tid + i * 256;          // float4 index, 0..4095
            const float4 v = xg[f];
            const int row = f >> 7, col4 = f & 127;
            const int kb = col4 >> 1, half = col4 & 1;
            ushort4 o;
            o.x = f2bf(v.x); o.y = f2bf(v.y); o.z = f2bf(v.z); o.w = f2bf(v.w);
            *(ushort4*)(smem + ((row * 64 + (kb ^ (row & 7))) << 4) + (half << 3)) = o;
        }
    }
    __syncthreads();

    const int r = rg * 16 + lrow;   // this lane's A-fragment row
    const int rs = r & 7;           // swizzle key

    // ---- h1 = relu(x @ W1 + b1): wave does rows rg*16, cols ch*128..+127 ----
    floatx4 acc[8];
    #pragma unroll
    for (int t = 0; t < 8; ++t) {
        const float bv = b1[ch * 128 + t * 16 + lrow];
        acc[t] = (floatx4){bv, bv, bv, bv};
    }
    for (int ks = 0; ks < 16; ++ks) {
        const bf16x8 a = *(const bf16x8*)(smem + ((r * 64 + ((ks * 4 + quad) ^ rs)) << 4));
        #pragma unroll
        for (int t = 0; t < 8; ++t) {
            const int n = ch * 128 + t * 16 + lrow;
            const bf16x8 b = *(const bf16x8*)(W1t + n * 512 + ks * 32 + quad * 8);
            acc[t] = __builtin_amdgcn_mfma_f32_16x16x32_bf16(a, b, acc[t], 0, 0, 0);
        }
    }
    // store h1 as bf16 A-layout into region2 (h2's A operand)
    #pragma unroll
    for (int t = 0; t < 8; ++t) {
        const int col = ch * 128 + t * 16 + lrow;
        #pragma unroll
        for (int g = 0; g < 4; ++g) {
            const int orow = rg * 16 + quad * 4 + g;
            const float v = fmaxf(acc[t][g], 0.0f);
            *(unsigned short*)(smem + 32768 +
                ((orow * 32 + ((col >> 3) ^ (orow & 7))) << 4) + ((col & 7) << 1)) = f2bf(v);
        }
    }

    // ---- xt = x @ thetas: wave does rows rg*16, cols (ch*2..+1)*16 ----
    floatx4 xtacc[2];
    xtacc[0] = (floatx4){0.f, 0.f, 0.f, 0.f};
    xtacc[1] = (floatx4){0.f, 0.f, 0.f, 0.f};
    for (int ks = 0; ks < 16; ++ks) {
        const bf16x8 a = *(const bf16x8*)(smem + ((r * 64 + ((ks * 4 + quad) ^ rs)) << 4));
        #pragma unroll
        for (int t = 0; t < 2; ++t) {
            const int n = (ch * 2 + t) * 16 + lrow;
            const bf16x8 b = *(const bf16x8*)(Tt + n * 512 + ks * 32 + quad * 8);
            xtacc[t] = __builtin_amdgcn_mfma_f32_16x16x32_bf16(a, b, xtacc[t], 0, 0, 0);
        }
    }
    __syncthreads();   // xA dead; h1A complete

    // xt -> region1 f32 [32][68]
    {
        float* xtf = (float*)smem;
        #pragma unroll
        for (int t = 0; t < 2; ++t) {
            const int col = (ch * 2 + t) * 16 + lrow;
            #pragma unroll
            for (int g = 0; g < 4; ++g)
                xtf[(rg * 16 + quad * 4 + g) * 68 + col] = xtacc[t][g];
        }
    }

    // ---- h2 = relu(h1 @ W2 + b2): rows rg*16, cols (ch*4..+3)*16 ----
    floatx4 acc2[4];
    #pragma unroll
    for (int t = 0; t < 4; ++t) {
        const float bv = b2[ch * 64 + t * 16 + lrow];
        acc2[t] = (floatx4){bv, bv, bv, bv};
    }
    for (int ks = 0; ks < 8; ++ks) {
        const bf16x8 a = *(const bf16x8*)(smem + 32768 + ((r * 32 + ((ks * 4 + quad) ^ rs)) << 4));
        #pragma unroll
        for (int t = 0; t < 4; ++t) {
            const int n = ch * 64 + t * 16 + lrow;
            const bf16x8 b = *(const bf16x8*)(W2t + n * 256 + ks * 32 + quad * 8);
            acc2[t] = __builtin_amdgcn_mfma_f32_16x16x32_bf16(a, b, acc2[t], 0, 0, 0);
        }
    }
    #pragma unroll
    for (int t = 0; t < 4; ++t) {
        const int col = ch * 64 + t * 16 + lrow;
        #pragma unroll
        for (int g = 0; g < 4; ++g) {
            const int orow = rg * 16 + quad * 4 + g;
            const float v = fmaxf(acc2[t][g], 0.0f);
            *(unsigned short*)(smem + 17408 +
                ((orow * 16 + ((col >> 3) ^ (orow & 7))) << 4) + ((col & 7) << 1)) = f2bf(v);
        }
    }
    __syncthreads();   // h2A complete

    // ---- logits = h2 @ W3 + b3: rows rg*16, cols (ch*2..+1)*16 ----
    floatx4 acc3[2];
    #pragma unroll
    for (int t = 0; t < 2; ++t) {
        const float bv = b3[ch * 32 + t * 16 + lrow];
        acc3[t] = (floatx4){bv, bv, bv, bv};
    }
    for (int ks = 0; ks < 4; ++ks) {
        const bf16x8 a = *(const bf16x8*)(smem + 17408 + ((r * 16 + ((ks * 4 + quad) ^ rs)) << 4));
        #pragma unroll
        for (int t = 0; t < 2; ++t) {
            const int n = ch * 32 + t * 16 + lrow;
            const bf16x8 b = *(const bf16x8*)(W3t + n * 128 + ks * 32 + quad * 8);
            acc3[t] = __builtin_amdgcn_mfma_f32_16x16x32_bf16(a, b, acc3[t], 0, 0, 0);
        }
    }
    {
        float* lgf = (float*)(smem + 8704);
        #pragma unroll
        for (int t = 0; t < 2; ++t) {
            const int col = ch * 32 + t * 16 + lrow;
            #pragma unroll
            for (int g = 0; g < 4; ++g)
                lgf[(rg * 16 + quad * 4 + g) * 68 + col] = acc3[t][g];
        }
    }
    __syncthreads();

    // ---- softmax + weighted sum + loss: wave handles rows w*8..+7, lane==k ----
    {
        const float* xtf = (const float*)smem;
        const float* lgf = (const float*)(smem + 8704);
        const int ep = *epoch_p;
        const float tmp = 10.0f * powf(0.01f, (float)ep * 0.001f);
        const float inv_temp = 1.0f / fmaxf(0.1f, tmp);

        float partial = 0.0f;
        #pragma unroll
        for (int rr = 0; rr < 8; ++rr) {
            const int rw  = w * 8 + rr;
            const int row = row0 + rw;
            const float uu = u[(size_t)row * Kn + lane];
            const float g  = -logf(-logf(uu));
            float s = (lgf[rw * 68 + lane] + g) * inv_temp;
            float m = s;
            #pragma unroll
            for (int off = 32; off > 0; off >>= 1)
                m = fmaxf(m, __shfl_xor(m, off));
            const float e = expf(s - m);
            float sum = e;
            #pragma unroll
            for (int off = 32; off > 0; off >>= 1)
                sum += __shfl_xor(sum, off);
            float v = (e / sum) * xtf[rw * 68 + lane];
            #pragma unroll
            for (int off = 32; off > 0; off >>= 1)
                v += __shfl_xor(v, off);
            if (lane == 0) {
                const float diff = v - label[row];
                partial = fmaf(diff, diff, partial);
            }
        }
        if (lane == 0)
            atomicAdd(out, partial * (1.0f / (float)Bn));
    }
}

extern "C" void kernel_launch(void* const* d_in, const int* in_sizes, int n_in,
                              void* d_out, int out_size, void* d_ws, size_t ws_size,
                              hipStream_t stream) {
    const float* x      = (const float*)d_in[0];
    const float* label  = (const float*)d_in[1];
    const float* u      = (const float*)d_in[2];
    const float* W1     = (const float*)d_in[3];
    const float* b1     = (const float*)d_in[4];
    const float* W2     = (const float*)d_in[5];
    const float* b2     = (const float*)d_in[6];
    const float* W3     = (const float*)d_in[7];
    const float* b3     = (const float*)d_in[8];
    const float* thetas = (const float*)d_in[9];
    const int*   epoch  = (const int*)d_in[10];
    float* out = (float*)d_out;

    unsigned short* wsb = (unsigned short*)d_ws;
    // prep: convert/transpose weights to bf16 (re-done every call; ws is re-poisoned)
    prep_k<<<800, 256, 0, stream>>>(W1, W2, W3, thetas, wsb, out);
    llp_mfma<<<Bn / BM, 256, 0, stream>>>(x, label, u, b1, b2, b3,
                                          wsb, wsb + 131072, wsb + 163840, wsb + 196608,
                                          epoch, out);
}